// Round 13
// baseline (137.544 us; speedup 1.0000x reference)
//
#include <hip/hip_runtime.h>

// CharGRU2: 2-layer GRU (reset_after=true) + dense + softmax, fp32.
// B=2048, T=128, V=256, H=20, L=15.
//
// Round 13: R11 structure (cross-layer pipeline L0(t=i)+L1(t=i-1), row-local
// DPP gate hops, 2 waves/SIMD) with the h-broadcast moved OFF the LDS pipe.
//
// R11/R12 diagnosis: 2 ds_write + 10 ds_read_b128 per wave-step = ~124 cyc of
// DS-pipe time; LDS is per-CU (8 waves) -> ~1024 cyc/CU-step vs wall 1076:
// the DS pipe was 95% SATURATED. That's why R12's latency-oriented register
// prefetch was neutral (throughput wall, not latency), and why VALUBusy was
// pinned at ~60%.
//
// Fix: h0/h1 live only in registers on their home lanes; broadcast via
// 40 v_readlane -> SGPRs per step (k-th home lane = 16*(k/5)+3*(k%5)+2,
// compile-time constants). Dots are v_fma_f32 v,s,v,v (1 SGPR operand is
// legal). ZERO LDS in the kernel. VALU is per-SIMD (2 waves) whereas DS was
// per-CU (8 waves) — trading 124 DS cyc for ~160 VALU cyc wins 4x on the
// shared-resource accounting.

#define BB 2048
#define TT 128
#define HH 20
#define LL 15
#define H3 60

// home lane of unit k (p3==2 lane of its triple, row-local)
#define HL(k) (16 * ((k) / 5) + 3 * ((k) % 5) + 2)

__device__ __forceinline__ float bclane(float v, int k) {
    return __int_as_float(__builtin_amdgcn_readlane(__float_as_int(v), k));
}
__device__ __forceinline__ float dpp_rshr1(float v) {
    // v_mov_b32_dpp row_shr:1 — lane i <- lane i-1 within its 16-lane row
    return __int_as_float(__builtin_amdgcn_update_dpp(
        0, __float_as_int(v), 0x111, 0xF, 0xF, true));
}
__device__ __forceinline__ float fast_rcp(float x) { return __builtin_amdgcn_rcpf(x); }
__device__ __forceinline__ float sigm(float x) { return fast_rcp(1.f + __expf(-x)); }
__device__ __forceinline__ float tanh_f(float x) { return 1.f - 2.f * fast_rcp(1.f + __expf(2.f * x)); }
#define PIN(v) asm volatile("" : "+v"(v))

extern "C" __global__ __launch_bounds__(256)
__attribute__((amdgpu_waves_per_eu(2, 2)))
void gru2_kernel(const int* __restrict__ x, const float* __restrict__ W0,
                 const float* __restrict__ U0, const float* __restrict__ b0i,
                 const float* __restrict__ b0r, const float* __restrict__ W1,
                 const float* __restrict__ U1, const float* __restrict__ b1i,
                 const float* __restrict__ b1r, const float* __restrict__ Wd,
                 const float* __restrict__ bd, float* __restrict__ out)
{
    const int lane = threadIdx.x & 63;
    const int b = blockIdx.x * 4 + (threadIdx.x >> 6);   // batch = wave id
    const int pos = lane & 15;                           // pos in DPP row
    const int pc  = (pos < 15) ? pos : 14;               // lane 16r+15 dups pos 14
    const int u   = pc / 3;                              // unit-in-row 0..4
    const int p3  = pc % 3;                              // 0:z 1:r 2:h~
    const int j   = (lane >> 4) * 5 + u;                 // unit 0..19
    const int col = p3 * 20 + j;                         // owned gate column

    // ---- weight columns into VGPRs, once, pinned ----
    float u0c[HH], w1c[HH], u1c[HH];
#pragma unroll
    for (int k = 0; k < HH; ++k) {
        u0c[k] = U0[k * H3 + col];
        w1c[k] = W1[k * H3 + col];
        u1c[k] = U1[k * H3 + col];
    }
#pragma unroll
    for (int k = 0; k < HH; ++k) { PIN(u0c[k]); PIN(w1c[k]); PIN(u1c[k]); }
    float bi0 = b0i[col], br0 = b0r[col], bi1 = b1i[col], br1 = b1r[col];
    PIN(bi0); PIN(br0); PIN(bi1); PIN(br1);

    // ---- tokens ----
    const int* xrow = x + b * TT;
    const int tokA = xrow[lane];
    const int tokB = xrow[64 + lane];

    float h0 = 0.f, h1 = 0.f;        // correct on home lanes (p3==2, pos<15)
    float hs0[HH], hs1[HH];          // uniform broadcast copies (SGPRs)
#pragma unroll
    for (int k = 0; k < HH; ++k) { hs0[k] = 0.f; hs1[k] = 0.f; }

    // ---- W0 pipeline: row t ready, row t+1 raw, token t+2 staged ----
    const int tok0 = __builtin_amdgcn_readlane(tokA, 0);
    const int tok1 = __builtin_amdgcn_readlane(tokA, 1);
    int tokn2 = __builtin_amdgcn_readlane(tokA, 2);
    float xw_cur = W0[tok0 * H3 + col] + bi0;
    float xw_nxt = W0[tok1 * H3 + col];

    // ---- prologue: L0 for t=0 (h0_{-1}=0 -> rec0 = br0) ----
    {
        const float pf = W0[tokn2 * H3 + col];
        const int tokn3 = __builtin_amdgcn_readlane(tokA, 3);
        const float rec0 = br0;
        const float sg0 = sigm(xw_cur + rec0);           // z on p=0, r on p=1
        const float rv0 = dpp_rshr1(sg0);                // home <- r_j
        const float zv0 = dpp_rshr1(rv0);                // home <- z_j
        const float hh0 = tanh_f(xw_cur + rv0 * rec0);
        h0 = fmaf(zv0, h0 - hh0, hh0);
#pragma unroll
        for (int k = 0; k < HH; ++k) hs0[k] = bclane(h0, HL(k));
        xw_cur = xw_nxt + bi0; xw_nxt = pf; tokn2 = tokn3;
    }

    // ---- main loop: i = 1..127, L0(t=i) + L1(t=i-1); dots from SGPRs ----
#pragma unroll 2
    for (int i = 1; i < TT; ++i) {
        const int t3 = (i + 3 < TT) ? (i + 3) : (TT - 1);
        const float pf = W0[tokn2 * H3 + col];
        const int tokn3 = __builtin_amdgcn_readlane(t3 < 64 ? tokA : tokB, t3 & 63);

        // three 20-deep dots, each split into two 10-deep chains
        float a0a = br0, a0b = 0.f;   // rec0 (L0 t=i)     <- hs0
        float a1a = bi1, a1b = 0.f;   // xw1  (L1 t=i-1)   <- hs0
        float a2a = br1, a2b = 0.f;   // rec1 (L1 t=i-1)   <- hs1
#pragma unroll
        for (int k = 0; k < 10; ++k) {
            a0a = fmaf(hs0[k], u0c[k], a0a);
            a1a = fmaf(hs0[k], w1c[k], a1a);
            a2a = fmaf(hs1[k], u1c[k], a2a);
        }
#pragma unroll
        for (int k = 10; k < HH; ++k) {
            a0b = fmaf(hs0[k], u0c[k], a0b);
            a1b = fmaf(hs0[k], w1c[k], a1b);
            a2b = fmaf(hs1[k], u1c[k], a2b);
        }
        const float rec0 = a0a + a0b;
        const float xw1  = a1a + a1b;
        const float rec1 = a2a + a2b;

        // ---- L0 gates (t=i): row-local DPP hops ----
        const float sg0 = sigm(xw_cur + rec0);
        const float rv0 = dpp_rshr1(sg0);
        const float zv0 = dpp_rshr1(rv0);
        const float hh0 = tanh_f(xw_cur + rv0 * rec0);
        h0 = fmaf(zv0, h0 - hh0, hh0);
        // broadcast fresh h0 for next iteration (hides behind L1 gates)
#pragma unroll
        for (int k = 0; k < HH; ++k) hs0[k] = bclane(h0, HL(k));

        // ---- L1 gates (t=i-1): independent of L0 above ----
        const float sg1 = sigm(xw1 + rec1);
        const float rv1 = dpp_rshr1(sg1);
        const float zv1 = dpp_rshr1(rv1);
        const float hh1 = tanh_f(xw1 + rv1 * rec1);
        h1 = fmaf(zv1, h1 - hh1, hh1);
        // broadcast fresh h1 for next iteration
#pragma unroll
        for (int k = 0; k < HH; ++k) hs1[k] = bclane(h1, HL(k));

        // rotate W0 pipeline
        xw_cur = xw_nxt + bi0; xw_nxt = pf; tokn2 = tokn3;
    }

    // ---- epilogue: L1 for t=127 (hs0 = h0_127, hs1 = h1_126) ----
    {
        float a1a = bi1, a1b = 0.f, a2a = br1, a2b = 0.f;
#pragma unroll
        for (int k = 0; k < 10; ++k) {
            a1a = fmaf(hs0[k], w1c[k], a1a);
            a2a = fmaf(hs1[k], u1c[k], a2a);
        }
#pragma unroll
        for (int k = 10; k < HH; ++k) {
            a1b = fmaf(hs0[k], w1c[k], a1b);
            a2b = fmaf(hs1[k], u1c[k], a2b);
        }
        const float xw1 = a1a + a1b, rec1 = a2a + a2b;
        const float sg1 = sigm(xw1 + rec1);
        const float rv1 = dpp_rshr1(sg1);
        const float zv1 = dpp_rshr1(rv1);
        const float hh1 = tanh_f(xw1 + rv1 * rec1);
        h1 = fmaf(zv1, h1 - hh1, hh1);
#pragma unroll
        for (int k = 0; k < HH; ++k) hs1[k] = bclane(h1, HL(k));
    }

    // ---- dense (h1 @ Wd + bd) + softmax, lanes 0..14 ----
    const int l = lane < LL ? lane : LL - 1;
    float acc = bd[l];
#pragma unroll
    for (int k = 0; k < HH; ++k)
        acc = fmaf(hs1[k], Wd[k * LL + l], acc);

    float m = acc;
#pragma unroll
    for (int i = 0; i < LL; ++i) m = fmaxf(m, bclane(acc, i));
    const float e = __expf(acc - m);
    float s = 0.f;
#pragma unroll
    for (int i = 0; i < LL; ++i) s += bclane(e, i);
    const float pr = e * fast_rcp(s);

    if (lane < LL) out[b * LL + lane] = pr;
}

extern "C" void kernel_launch(void* const* d_in, const int* in_sizes, int n_in,
                              void* d_out, int out_size, void* d_ws, size_t ws_size,
                              hipStream_t stream) {
    const int*   x   = (const int*)  d_in[0];
    const float* W0  = (const float*)d_in[1];
    const float* U0  = (const float*)d_in[2];
    const float* b0i = (const float*)d_in[3];
    const float* b0r = (const float*)d_in[4];
    const float* W1  = (const float*)d_in[5];
    const float* U1  = (const float*)d_in[6];
    const float* b1i = (const float*)d_in[7];
    const float* b1r = (const float*)d_in[8];
    const float* Wd  = (const float*)d_in[9];
    const float* bd  = (const float*)d_in[10];
    // d_in[11] = drop_rate (identity), unused
    float* out = (float*)d_out;

    // 1 batch/wave, 4 waves/block -> 512 blocks = 2 blocks/CU = 2 waves/SIMD.
    dim3 grid(BB / 4), block(256);
    hipLaunchKernelGGL(gru2_kernel, grid, block, 0, stream,
                       x, W0, U0, b0i, b0r, W1, U1, b1i, b1r, Wd, bd, out);
}